// Round 13
// baseline (181.597 us; speedup 1.0000x reference)
//
#include <hip/hip_runtime.h>
#include <math.h>

#define N_POINTS 4000000
#define N_PLANES 64
#define THRESH   0.02f
#define NVALS    (N_PLANES*10)              // 640
#define PPT      16                         // points per lane (8 packed pairs)
#define NPAIR    (PPT/2)
#define BLKPTS   (PPT*64)                   // 1024 points per item
#define G1       2048                       // reduce grid (8 blocks/CU exactly)
#define ITEMS    2                          // items per block (uniform)
#define NPB      (G1*ITEMS)                 // 4096 items
#define NPAD     (NPB*BLKPTS - N_POINTS)    // 194,304 zero-padded points
#define FULL_PB  (N_POINTS/BLKPTS)          // 3906: items < this are fully valid
#define SEG_R    16                         // rotations per item
#define RTHR     256                        // 4 waves per block

typedef float v2f __attribute__((ext_vector_type(2)));

// ---- packed fp32 primitives (VOP3P) ----
__device__ __forceinline__ v2f pk_fma(v2f a, v2f b, v2f c) {
    v2f d; asm("v_pk_fma_f32 %0, %1, %2, %3" : "=v"(d) : "v"(a), "v"(b), "v"(c)); return d;
}
__device__ __forceinline__ v2f pk_mul(v2f a, v2f b) {
    v2f d; asm("v_pk_mul_f32 %0, %1, %2" : "=v"(d) : "v"(a), "v"(b)); return d;
}
__device__ __forceinline__ v2f pk_mul_clamp(v2f a, v2f b) {
    v2f d; asm("v_pk_mul_f32 %0, %1, %2 clamp" : "=v"(d) : "v"(a), "v"(b)); return d;
}
__device__ __forceinline__ void pk_adda(v2f& acc, v2f a) {
    asm("v_pk_add_f32 %0, %1, %0" : "+v"(acc) : "v"(a));
}
__device__ __forceinline__ void pk_fmaa(v2f& acc, v2f a, v2f b) {
    asm("v_pk_fma_f32 %0, %1, %2, %0" : "+v"(acc) : "v"(a), "v"(b));
}
__device__ __forceinline__ float bperm(int addr, float v) {
    return __uint_as_float(__builtin_amdgcn_ds_bpermute(addr, __float_as_uint(v)));
}

// ---------------------------------------------------------------------------
// Stage 1: systolic-rotation moment reduction, packed fp32, 8 blocks/CU.
// Lane l holds 8 point-pairs (v2f) + one resident plane (splatted params +
// 10 packed f32 acc). Inner body = 18 pk inst per pair (9/point). Every 16
// point-passes the plane state rotates one lane via 14 ds_bpermute (merge ->
// scalar bperm -> re-expand). Coverage: wave w covers a disjoint 16-lane
// segment per item for every plane; ITEMS items x 16 rotations per block.
// Dump: after 16*ITEMS rotations lane l holds plane (l+16*wid+16*ITEMS)&63.
// Zero-pads contribute only to cnt iff fmaf(d,d,-TH^2)<0; finalize subtracts.
// ---------------------------------------------------------------------------
__global__ __launch_bounds__(RTHR, 4)
void reduce_kernel(const float* __restrict__ pts,
                   const float* __restrict__ nrm,
                   const float* __restrict__ dst,
                   float* __restrict__ partials)
{
    const int lane = threadIdx.x & 63;
    const int wid  = threadIdx.x >> 6;

    __shared__ float part[RTHR/64][NVALS];

    const int rotaddr = ((lane + 1) & 63) << 2;   // pull from lane+1

    const v2f TH2N2 = { -(THRESH*THRESH), -(THRESH*THRESH) };
    const v2f NBIG2 = { -1e20f, -1e20f };

    // resident plane (start plane (lane + 16*wid)), splatted
    v2f nx2, ny2, nz2, nd2;
    {
        const int q = (lane + SEG_R * wid) & 63;
        const float a = nrm[q*3+0], b = nrm[q*3+1], c = nrm[q*3+2], d = -dst[q];
        nx2 = (v2f){a,a}; ny2 = (v2f){b,b}; nz2 = (v2f){c,c}; nd2 = (v2f){d,d};
    }

    v2f a2[10];
#pragma unroll
    for (int i = 0; i < 10; ++i) a2[i] = (v2f){0.f, 0.f};

    v2f PX2[NPAIR], PY2[NPAIR], PZ2[NPAIR];

    for (int it = 0; it < ITEMS; ++it) {
        const int pb = blockIdx.x * ITEMS + it;
        const float* P0 = pts + ((size_t)pb * BLKPTS + lane) * 3;

        if (pb < FULL_PB) {                       // fully valid (fast path)
#pragma unroll
            for (int v = 0; v < NPAIR; ++v) {
                PX2[v] = (v2f){ P0[(2*v)*192+0], P0[(2*v+1)*192+0] };
                PY2[v] = (v2f){ P0[(2*v)*192+1], P0[(2*v+1)*192+1] };
                PZ2[v] = (v2f){ P0[(2*v)*192+2], P0[(2*v+1)*192+2] };
            }
        } else if (pb == FULL_PB) {               // points valid only for u<4
#pragma unroll
            for (int v = 0; v < NPAIR; ++v) {
                if (v < 2) {
                    PX2[v] = (v2f){ P0[(2*v)*192+0], P0[(2*v+1)*192+0] };
                    PY2[v] = (v2f){ P0[(2*v)*192+1], P0[(2*v+1)*192+1] };
                    PZ2[v] = (v2f){ P0[(2*v)*192+2], P0[(2*v+1)*192+2] };
                } else {
                    PX2[v] = (v2f){0.f,0.f}; PY2[v] = (v2f){0.f,0.f}; PZ2[v] = (v2f){0.f,0.f};
                }
            }
        } else {                                  // pure pad item
#pragma unroll
            for (int v = 0; v < NPAIR; ++v) {
                PX2[v] = (v2f){0.f,0.f}; PY2[v] = (v2f){0.f,0.f}; PZ2[v] = (v2f){0.f,0.f};
            }
        }

#pragma unroll 1
        for (int r = 0; r < SEG_R; ++r) {
#pragma unroll
            for (int v = 0; v < NPAIR; ++v) {
                const v2f t2  = pk_fma(PX2[v], nx2, pk_fma(PY2[v], ny2, pk_fma(PZ2[v], nz2, nd2)));
                const v2f d2  = pk_fma(t2, t2, TH2N2);        // t^2 - TH^2
                const v2f fm2 = pk_mul_clamp(d2, NBIG2);      // 1 iff t^2 < TH^2, else 0
                const v2f tx2 = pk_mul(PX2[v], fm2);
                const v2f ty2 = pk_mul(PY2[v], fm2);
                const v2f tz2 = pk_mul(PZ2[v], fm2);
                pk_adda(a2[0], fm2);
                pk_adda(a2[1], tx2); pk_adda(a2[2], ty2); pk_adda(a2[3], tz2);
                pk_fmaa(a2[4], tx2, PX2[v]); pk_fmaa(a2[5], tx2, PY2[v]); pk_fmaa(a2[6], tx2, PZ2[v]);
                pk_fmaa(a2[7], ty2, PY2[v]); pk_fmaa(a2[8], ty2, PZ2[v]); pk_fmaa(a2[9], tz2, PZ2[v]);
            }
            // rotate: merge packed acc -> 10 scalar bperms -> re-expand {s, 0}
            float s[10];
#pragma unroll
            for (int i = 0; i < 10; ++i) s[i] = a2[i].x + a2[i].y;
#pragma unroll
            for (int i = 0; i < 10; ++i) s[i] = bperm(rotaddr, s[i]);
#pragma unroll
            for (int i = 0; i < 10; ++i) a2[i] = (v2f){ s[i], 0.f };
            // rotate plane splats (lo half via bperm, copy to hi)
            nx2.x = bperm(rotaddr, nx2.x); nx2.y = nx2.x;
            ny2.x = bperm(rotaddr, ny2.x); ny2.y = ny2.x;
            nz2.x = bperm(rotaddr, nz2.x); nz2.y = nz2.x;
            nd2.x = bperm(rotaddr, nd2.x); nd2.y = nd2.x;
        }
    }

    // after 16*ITEMS rotations lane l holds the block-total for plane
    // (l + 16*wid + 16*ITEMS) & 63
    {
        const int wp = (lane + SEG_R * (wid + ITEMS)) & 63;
        float* rr = &part[wid][wp * 10];
#pragma unroll
        for (int i = 0; i < 10; ++i) rr[i] = a2[i].x + a2[i].y;
    }
    __syncthreads();
    for (int v = threadIdx.x; v < NVALS; v += RTHR) {
        float sum = 0.f;
#pragma unroll
        for (int ww = 0; ww < RTHR/64; ++ww) sum += part[ww][v];
        partials[(long long)blockIdx.x * NVALS + v] = sum;
    }
}

// ---------------------------------------------------------------------------
// Stage 2 (fused fit): one block per plane. Stream partials, f64-accumulate,
// subtract the zero-pad cnt contamination (bit-identical predicate to the
// kernel's packed mask), then thread 0 runs the 3x3 Jacobi eigensolve and
// writes the merged param row {nx,ny,nz,-d, vld*rx,vld*ry,vld*rz, -vld*rd}.
// ---------------------------------------------------------------------------
__global__ __launch_bounds__(256)
void finalize_kernel(const float* __restrict__ partials, int nb,
                     const float* __restrict__ nrm,
                     const float* __restrict__ dst,
                     float* __restrict__ params)
{
    const int p    = blockIdx.x;
    const int lane = threadIdx.x & 63;
    const int wid  = threadIdx.x >> 6;

    double s[10];
#pragma unroll
    for (int q = 0; q < 10; ++q) s[q] = 0.0;

    for (int b = threadIdx.x; b < nb; b += 256) {
        const float* row = partials + (long long)b * NVALS + p * 10;
#pragma unroll
        for (int q = 0; q < 10; ++q) s[q] += (double)row[q];
    }

#pragma unroll
    for (int off = 32; off; off >>= 1)
#pragma unroll
        for (int q = 0; q < 10; ++q) s[q] += __shfl_xor(s[q], off);

    __shared__ double wsum[4][10];
    if (lane == 0) {
#pragma unroll
        for (int q = 0; q < 10; ++q) wsum[wid][q] = s[q];
    }
    __syncthreads();
    if (threadIdx.x != 0) return;

    double acc[10];
#pragma unroll
    for (int q = 0; q < 10; ++q)
        acc[q] = wsum[0][q] + wsum[1][q] + wsum[2][q] + wsum[3][q];

    double cnt = acc[0];
    // pad points (0,0,0): t = -d; mask = clamp((t^2 - TH^2) * -1e20) = 1
    if (fmaf(dst[p], dst[p], -(THRESH*THRESH)) < 0.0f) cnt -= (double)NPAD;

    const double sx = acc[1], sy = acc[2], sz = acc[3];
    const double den = fmax(cnt, 1.0);
    const double cx = sx / den, cy = sy / den, cz = sz / den;

    double C[3][3];
    C[0][0] = acc[4] - 2.0*cx*sx + cnt*cx*cx;
    C[0][1] = acc[5] - cx*sy - cy*sx + cnt*cx*cy;
    C[0][2] = acc[6] - cx*sz - cz*sx + cnt*cx*cz;
    C[1][1] = acc[7] - 2.0*cy*sy + cnt*cy*cy;
    C[1][2] = acc[8] - cy*sz - cz*sy + cnt*cy*cz;
    C[2][2] = acc[9] - 2.0*cz*sz + cnt*cz*cz;
    C[1][0] = C[0][1]; C[2][0] = C[0][2]; C[2][1] = C[1][2];

    const double valid = (cnt >= 3.0) ? 1.0 : 0.0;
    C[0][0] += (1.0 - valid) * 1.0;
    C[1][1] += (1.0 - valid) * 2.0;
    C[2][2] += (1.0 - valid) * 3.0;

    double V[3][3] = {{1,0,0},{0,1,0},{0,0,1}};
    for (int sweep = 0; sweep < 15; ++sweep) {
#pragma unroll
        for (int k = 0; k < 3; ++k) {
            const int pp = (k == 2) ? 1 : 0;
            const int qq = (k == 0) ? 1 : 2;
            const int rr = 3 - pp - qq;
            const double apq = C[pp][qq];
            if (fabs(apq) < 1e-300) continue;
            const double theta = (C[qq][qq] - C[pp][pp]) / (2.0 * apq);
            const double t = copysign(1.0, theta) / (fabs(theta) + sqrt(theta*theta + 1.0));
            const double c = 1.0 / sqrt(t*t + 1.0);
            const double ss = t * c;
            const double app = C[pp][pp], aqq = C[qq][qq];
            const double arp = C[rr][pp], arq = C[rr][qq];
            C[pp][pp] = app - t * apq;
            C[qq][qq] = aqq + t * apq;
            C[pp][qq] = 0.0; C[qq][pp] = 0.0;
            const double nrp = c*arp - ss*arq;
            const double nrq = ss*arp + c*arq;
            C[rr][pp] = nrp; C[pp][rr] = nrp;
            C[rr][qq] = nrq; C[qq][rr] = nrq;
#pragma unroll
            for (int i = 0; i < 3; ++i) {
                const double vip = V[i][pp], viq = V[i][qq];
                V[i][pp] = c*vip - ss*viq;
                V[i][qq] = ss*vip + c*viq;
            }
        }
    }

    int idx = 0;
    if (C[1][1] < C[idx][idx]) idx = 1;
    if (C[2][2] < C[idx][idx]) idx = 2;
    double rx = V[0][idx], ry = V[1][idx], rz = V[2][idx];
    const double inv = 1.0 / sqrt(rx*rx + ry*ry + rz*rz);
    rx *= inv; ry *= inv; rz *= inv;

    const double nxd = (double)nrm[p*3+0];
    const double nyd = (double)nrm[p*3+1];
    const double nzd = (double)nrm[p*3+2];
    if (rx*nxd + ry*nyd + rz*nzd < 0.0) { rx = -rx; ry = -ry; rz = -rz; }
    const double rd = cx*rx + cy*ry + cz*rz;

    const float vldf = (float)valid;
    params[p*8+0] = nrm[p*3+0];
    params[p*8+1] = nrm[p*3+1];
    params[p*8+2] = nrm[p*3+2];
    params[p*8+3] = -dst[p];
    params[p*8+4] = vldf * (float)rx;
    params[p*8+5] = vldf * (float)ry;
    params[p*8+6] = vldf * (float)rz;
    params[p*8+7] = -(vldf * (float)rd);
}

// ---------------------------------------------------------------------------
// Stage 3: packed projection, 8 points per thread as 4 pairs (13 pk-inst per
// pair per plane). Same t-chains as before; mask via the packed clamp trick.
// ---------------------------------------------------------------------------
#define PPTH 8
#define PQ   (N_POINTS / PPTH)   // 500,000

__global__ __launch_bounds__(256)
void project_kernel(const float* __restrict__ pts,
                    const float* __restrict__ params,
                    float* __restrict__ out)
{
    const int tid = blockIdx.x * 256 + threadIdx.x;
    if (tid >= PQ) return;

    const v2f TH2N2 = { -(THRESH*THRESH), -(THRESH*THRESH) };
    const v2f NBIG2 = { -1e20f, -1e20f };
    const v2f NEG12 = { -1.f, -1.f };

    v2f ox2[4], oy2[4], oz2[4], qx2[4], qy2[4], qz2[4];
#pragma unroll
    for (int k = 0; k < 4; ++k) {
        const long long i0 = (long long)tid + (long long)(2*k)   * PQ;
        const long long i1 = (long long)tid + (long long)(2*k+1) * PQ;
        ox2[k] = (v2f){ pts[i0*3+0], pts[i1*3+0] };
        oy2[k] = (v2f){ pts[i0*3+1], pts[i1*3+1] };
        oz2[k] = (v2f){ pts[i0*3+2], pts[i1*3+2] };
        qx2[k] = ox2[k]; qy2[k] = oy2[k]; qz2[k] = oz2[k];
    }

#pragma unroll 2
    for (int p = 0; p < N_PLANES; ++p) {
        const float nx  = params[p*8+0];
        const float ny  = params[p*8+1];
        const float nz  = params[p*8+2];
        const float md  = params[p*8+3];   // -d
        const float rvx = params[p*8+4];   // vld*rx
        const float rvy = params[p*8+5];
        const float rvz = params[p*8+6];
        const float mrd = params[p*8+7];   // -vld*rd
        const v2f nx2  = (v2f){nx,nx},   ny2  = (v2f){ny,ny},   nz2 = (v2f){nz,nz};
        const v2f md2  = (v2f){md,md},   mrd2 = (v2f){mrd,mrd};
        const v2f rvx2 = (v2f){rvx,rvx}, rvy2 = (v2f){rvy,rvy}, rvz2 = (v2f){rvz,rvz};

#pragma unroll
        for (int k = 0; k < 4; ++k) {
            const v2f t0  = pk_fma(ox2[k], nx2, pk_fma(oy2[k], ny2, pk_fma(oz2[k], nz2, md2)));
            const v2f d2  = pk_fma(t0, t0, TH2N2);
            const v2f fm2 = pk_mul_clamp(d2, NBIG2);
            const v2f tt  = pk_fma(qx2[k], rvx2, pk_fma(qy2[k], rvy2, pk_fma(qz2[k], rvz2, mrd2)));
            const v2f ftn = pk_mul(pk_mul(tt, fm2), NEG12);   // -fm*t
            qx2[k] = pk_fma(ftn, rvx2, qx2[k]);
            qy2[k] = pk_fma(ftn, rvy2, qy2[k]);
            qz2[k] = pk_fma(ftn, rvz2, qz2[k]);
        }
    }

#pragma unroll
    for (int k = 0; k < 4; ++k) {
        const long long i0 = (long long)tid + (long long)(2*k)   * PQ;
        const long long i1 = (long long)tid + (long long)(2*k+1) * PQ;
        out[i0*3+0] = qx2[k].x; out[i0*3+1] = qy2[k].x; out[i0*3+2] = qz2[k].x;
        out[i1*3+0] = qx2[k].y; out[i1*3+1] = qy2[k].y; out[i1*3+2] = qz2[k].y;
    }
}

// ---------------------------------------------------------------------------
extern "C" void kernel_launch(void* const* d_in, const int* in_sizes, int n_in,
                              void* d_out, int out_size, void* d_ws, size_t ws_size,
                              hipStream_t stream)
{
    const float* pts = (const float*)d_in[0];
    const float* nrm = (const float*)d_in[1];
    const float* dst = (const float*)d_in[2];
    float* out = (float*)d_out;

    float* partials = (float*)d_ws;                         // G1 x 640 f32 (5.24 MB)
    size_t poff = ((size_t)G1 * NVALS * sizeof(float) + 255) & ~(size_t)255;
    float* params = (float*)((char*)d_ws + poff);

    hipLaunchKernelGGL(reduce_kernel, dim3(G1), dim3(RTHR), 0, stream,
                       pts, nrm, dst, partials);
    hipLaunchKernelGGL(finalize_kernel, dim3(N_PLANES), dim3(256), 0, stream,
                       partials, G1, nrm, dst, params);
    hipLaunchKernelGGL(project_kernel, dim3((PQ + 255) / 256), dim3(256), 0, stream,
                       pts, params, out);
}

// Round 14
// 172.215 us; speedup vs baseline: 1.0545x; 1.0545x over previous
//
#include <hip/hip_runtime.h>
#include <math.h>

#define N_POINTS 4000000
#define N_PLANES 64
#define THRESH   0.02f
#define NVALS    (N_PLANES*10)              // 640
#define PPT      16                         // points per lane (8 packed pairs)
#define NPAIR    (PPT/2)
#define BLKPTS   (PPT*64)                   // 1024 points per item
#define G1       2048                       // reduce grid
#define ITEMS    2                          // items per block (uniform)
#define NPB      (G1*ITEMS)                 // 4096 items
#define NPAD     (NPB*BLKPTS - N_POINTS)    // 194,304 zero-padded points
#define FULL_PB  (N_POINTS/BLKPTS)          // 3906: items < this are fully valid
#define SEG_R    16                         // rotations per item
#define RTHR     256                        // 4 waves per block

typedef float v2f __attribute__((ext_vector_type(2)));

// ---- packed fp32 primitives (VOP3P) ----
__device__ __forceinline__ v2f pk_fma(v2f a, v2f b, v2f c) {
    v2f d; asm("v_pk_fma_f32 %0, %1, %2, %3" : "=v"(d) : "v"(a), "v"(b), "v"(c)); return d;
}
__device__ __forceinline__ v2f pk_fma_n0(v2f a, v2f b, v2f c) {   // d = -a*b + c
    v2f d; asm("v_pk_fma_f32 %0, %1, %2, %3 neg_lo:[1,0,0] neg_hi:[1,0,0]"
               : "=v"(d) : "v"(a), "v"(b), "v"(c)); return d;
}
__device__ __forceinline__ v2f pk_mul(v2f a, v2f b) {
    v2f d; asm("v_pk_mul_f32 %0, %1, %2" : "=v"(d) : "v"(a), "v"(b)); return d;
}
__device__ __forceinline__ v2f pk_mul_clamp(v2f a, v2f b) {
    v2f d; asm("v_pk_mul_f32 %0, %1, %2 clamp" : "=v"(d) : "v"(a), "v"(b)); return d;
}
__device__ __forceinline__ void pk_adda(v2f& acc, v2f a) {
    asm("v_pk_add_f32 %0, %1, %0" : "+v"(acc) : "v"(a));
}
__device__ __forceinline__ void pk_fmaa(v2f& acc, v2f a, v2f b) {
    asm("v_pk_fma_f32 %0, %1, %2, %0" : "+v"(acc) : "v"(a), "v"(b));
}
__device__ __forceinline__ float bperm(int addr, float v) {
    return __uint_as_float(__builtin_amdgcn_ds_bpermute(addr, __float_as_uint(v)));
}

// ---------------------------------------------------------------------------
// Stage 1: systolic-rotation moment reduction, packed fp32, async rotation.
// Lane l holds 8 point-pairs + the resident plane (splatted params). Fresh
// packed partials b0..b9 per rotation (pair-0-seeded); carried scalar tot[10]
// rotates one lane per boundary via 10 ds_bpermute whose results are not
// needed until the NEXT boundary (a full point-pass of cover -> no exposed
// DS latency). Plane params for the next rotation are loaded directly from
// nrm/dst (VMEM pipe, L1-hot, prefetched before the point loop).
// Coverage identical to r13; zero-pads contribute only to cnt iff
// fmaf(d,d,-TH^2)<0, which finalize subtracts exactly.
// ---------------------------------------------------------------------------
__global__ __launch_bounds__(RTHR, 4)
void reduce_kernel(const float* __restrict__ pts,
                   const float* __restrict__ nrm,
                   const float* __restrict__ dst,
                   float* __restrict__ partials)
{
    const int lane = threadIdx.x & 63;
    const int wid  = threadIdx.x >> 6;

    __shared__ float part[RTHR/64][NVALS];

    const int rotaddr = ((lane + 1) & 63) << 2;   // pull from lane+1

    const v2f TH2N2 = { -(THRESH*THRESH), -(THRESH*THRESH) };
    const v2f NBIG2 = { -1e20f, -1e20f };

    // resident plane index and its params (start plane (lane + 16*wid))
    int q = (lane + SEG_R * wid) & 63;
    float pnx = nrm[q*3+0], pny = nrm[q*3+1], pnz = nrm[q*3+2], pnd = -dst[q];

    float tot[10];
#pragma unroll
    for (int i = 0; i < 10; ++i) tot[i] = 0.f;

    v2f PX2[NPAIR], PY2[NPAIR], PZ2[NPAIR];

    for (int it = 0; it < ITEMS; ++it) {
        const int pb = blockIdx.x * ITEMS + it;
        const float* P0 = pts + ((size_t)pb * BLKPTS + lane) * 3;

        if (pb < FULL_PB) {                       // fully valid (fast path)
#pragma unroll
            for (int v = 0; v < NPAIR; ++v) {
                PX2[v] = (v2f){ P0[(2*v)*192+0], P0[(2*v+1)*192+0] };
                PY2[v] = (v2f){ P0[(2*v)*192+1], P0[(2*v+1)*192+1] };
                PZ2[v] = (v2f){ P0[(2*v)*192+2], P0[(2*v+1)*192+2] };
            }
        } else if (pb == FULL_PB) {               // first 256 points valid: v<2
#pragma unroll
            for (int v = 0; v < NPAIR; ++v) {
                if (v < 2) {
                    PX2[v] = (v2f){ P0[(2*v)*192+0], P0[(2*v+1)*192+0] };
                    PY2[v] = (v2f){ P0[(2*v)*192+1], P0[(2*v+1)*192+1] };
                    PZ2[v] = (v2f){ P0[(2*v)*192+2], P0[(2*v+1)*192+2] };
                } else {
                    PX2[v] = (v2f){0.f,0.f}; PY2[v] = (v2f){0.f,0.f}; PZ2[v] = (v2f){0.f,0.f};
                }
            }
        } else {                                  // pure pad item
#pragma unroll
            for (int v = 0; v < NPAIR; ++v) {
                PX2[v] = (v2f){0.f,0.f}; PY2[v] = (v2f){0.f,0.f}; PZ2[v] = (v2f){0.f,0.f};
            }
        }

#pragma unroll 1
        for (int r = 0; r < SEG_R; ++r) {
            const v2f nx2 = {pnx,pnx}, ny2 = {pny,pny}, nz2 = {pnz,pnz}, nd2 = {pnd,pnd};
            // prefetch next rotation's params (VMEM, hidden under point loop)
            const int qn = (q + 1) & 63;
            const float fnx = nrm[qn*3+0];
            const float fny = nrm[qn*3+1];
            const float fnz = nrm[qn*3+2];
            const float fnd = -dst[qn];

            v2f b0,b1,b2,b3,b4,b5,b6,b7,b8,b9;
            {   // pair 0 seeds the partials (no zero-init)
                const v2f t2  = pk_fma(PX2[0], nx2, pk_fma(PY2[0], ny2, pk_fma(PZ2[0], nz2, nd2)));
                const v2f d2  = pk_fma(t2, t2, TH2N2);        // t^2 - TH^2
                const v2f fm2 = pk_mul_clamp(d2, NBIG2);      // 1 iff t^2 < TH^2, else 0
                const v2f tx2 = pk_mul(PX2[0], fm2);
                const v2f ty2 = pk_mul(PY2[0], fm2);
                const v2f tz2 = pk_mul(PZ2[0], fm2);
                b0 = fm2; b1 = tx2; b2 = ty2; b3 = tz2;
                b4 = pk_mul(tx2, PX2[0]); b5 = pk_mul(tx2, PY2[0]); b6 = pk_mul(tx2, PZ2[0]);
                b7 = pk_mul(ty2, PY2[0]); b8 = pk_mul(ty2, PZ2[0]); b9 = pk_mul(tz2, PZ2[0]);
            }
#pragma unroll
            for (int v = 1; v < NPAIR; ++v) {
                const v2f t2  = pk_fma(PX2[v], nx2, pk_fma(PY2[v], ny2, pk_fma(PZ2[v], nz2, nd2)));
                const v2f d2  = pk_fma(t2, t2, TH2N2);
                const v2f fm2 = pk_mul_clamp(d2, NBIG2);
                const v2f tx2 = pk_mul(PX2[v], fm2);
                const v2f ty2 = pk_mul(PY2[v], fm2);
                const v2f tz2 = pk_mul(PZ2[v], fm2);
                pk_adda(b0, fm2);
                pk_adda(b1, tx2); pk_adda(b2, ty2); pk_adda(b3, tz2);
                pk_fmaa(b4, tx2, PX2[v]); pk_fmaa(b5, tx2, PY2[v]); pk_fmaa(b6, tx2, PZ2[v]);
                pk_fmaa(b7, ty2, PY2[v]); pk_fmaa(b8, ty2, PZ2[v]); pk_fmaa(b9, tz2, PZ2[v]);
            }

            // fold this rotation's partials into the carried totals, then
            // launch the rotation; the bperm results are not needed until the
            // NEXT fold (after the next 140-inst point loop) -> latency hidden.
            tot[0] += b0.x + b0.y; tot[1] += b1.x + b1.y; tot[2] += b2.x + b2.y;
            tot[3] += b3.x + b3.y; tot[4] += b4.x + b4.y; tot[5] += b5.x + b5.y;
            tot[6] += b6.x + b6.y; tot[7] += b7.x + b7.y; tot[8] += b8.x + b8.y;
            tot[9] += b9.x + b9.y;
#pragma unroll
            for (int i = 0; i < 10; ++i) tot[i] = bperm(rotaddr, tot[i]);

            pnx = fnx; pny = fny; pnz = fnz; pnd = fnd; q = qn;
        }
    }

    // after 16*ITEMS rotations lane l holds the block-total for plane
    // (l + 16*wid + 16*ITEMS) & 63
    {
        const int wp = (lane + SEG_R * (wid + ITEMS)) & 63;
        float* rr = &part[wid][wp * 10];
#pragma unroll
        for (int i = 0; i < 10; ++i) rr[i] = tot[i];
    }
    __syncthreads();
    for (int v = threadIdx.x; v < NVALS; v += RTHR) {
        float sum = 0.f;
#pragma unroll
        for (int ww = 0; ww < RTHR/64; ++ww) sum += part[ww][v];
        partials[(long long)blockIdx.x * NVALS + v] = sum;
    }
}

// ---------------------------------------------------------------------------
// Stage 2 (fused fit): one block per plane. Stream partials, f64-accumulate,
// subtract the zero-pad cnt contamination (bit-identical predicate to the
// kernel's packed mask), then thread 0 runs the 3x3 Jacobi eigensolve and
// writes the merged param row {nx,ny,nz,-d, vld*rx,vld*ry,vld*rz, -vld*rd}.
// ---------------------------------------------------------------------------
__global__ __launch_bounds__(256)
void finalize_kernel(const float* __restrict__ partials, int nb,
                     const float* __restrict__ nrm,
                     const float* __restrict__ dst,
                     float* __restrict__ params)
{
    const int p    = blockIdx.x;
    const int lane = threadIdx.x & 63;
    const int wid  = threadIdx.x >> 6;

    double s[10];
#pragma unroll
    for (int q = 0; q < 10; ++q) s[q] = 0.0;

    for (int b = threadIdx.x; b < nb; b += 256) {
        const float* row = partials + (long long)b * NVALS + p * 10;
#pragma unroll
        for (int q = 0; q < 10; ++q) s[q] += (double)row[q];
    }

#pragma unroll
    for (int off = 32; off; off >>= 1)
#pragma unroll
        for (int q = 0; q < 10; ++q) s[q] += __shfl_xor(s[q], off);

    __shared__ double wsum[4][10];
    if (lane == 0) {
#pragma unroll
        for (int q = 0; q < 10; ++q) wsum[wid][q] = s[q];
    }
    __syncthreads();
    if (threadIdx.x != 0) return;

    double acc[10];
#pragma unroll
    for (int q = 0; q < 10; ++q)
        acc[q] = wsum[0][q] + wsum[1][q] + wsum[2][q] + wsum[3][q];

    double cnt = acc[0];
    // pad points (0,0,0): t = -d; mask = clamp((t^2 - TH^2) * -1e20) = 1
    if (fmaf(dst[p], dst[p], -(THRESH*THRESH)) < 0.0f) cnt -= (double)NPAD;

    const double sx = acc[1], sy = acc[2], sz = acc[3];
    const double den = fmax(cnt, 1.0);
    const double cx = sx / den, cy = sy / den, cz = sz / den;

    double C[3][3];
    C[0][0] = acc[4] - 2.0*cx*sx + cnt*cx*cx;
    C[0][1] = acc[5] - cx*sy - cy*sx + cnt*cx*cy;
    C[0][2] = acc[6] - cx*sz - cz*sx + cnt*cx*cz;
    C[1][1] = acc[7] - 2.0*cy*sy + cnt*cy*cy;
    C[1][2] = acc[8] - cy*sz - cz*sy + cnt*cy*cz;
    C[2][2] = acc[9] - 2.0*cz*sz + cnt*cz*cz;
    C[1][0] = C[0][1]; C[2][0] = C[0][2]; C[2][1] = C[1][2];

    const double valid = (cnt >= 3.0) ? 1.0 : 0.0;
    C[0][0] += (1.0 - valid) * 1.0;
    C[1][1] += (1.0 - valid) * 2.0;
    C[2][2] += (1.0 - valid) * 3.0;

    double V[3][3] = {{1,0,0},{0,1,0},{0,0,1}};
    for (int sweep = 0; sweep < 15; ++sweep) {
#pragma unroll
        for (int k = 0; k < 3; ++k) {
            const int pp = (k == 2) ? 1 : 0;
            const int qq = (k == 0) ? 1 : 2;
            const int rr = 3 - pp - qq;
            const double apq = C[pp][qq];
            if (fabs(apq) < 1e-300) continue;
            const double theta = (C[qq][qq] - C[pp][pp]) / (2.0 * apq);
            const double t = copysign(1.0, theta) / (fabs(theta) + sqrt(theta*theta + 1.0));
            const double c = 1.0 / sqrt(t*t + 1.0);
            const double ss = t * c;
            const double app = C[pp][pp], aqq = C[qq][qq];
            const double arp = C[rr][pp], arq = C[rr][qq];
            C[pp][pp] = app - t * apq;
            C[qq][qq] = aqq + t * apq;
            C[pp][qq] = 0.0; C[qq][pp] = 0.0;
            const double nrp = c*arp - ss*arq;
            const double nrq = ss*arp + c*arq;
            C[rr][pp] = nrp; C[pp][rr] = nrp;
            C[rr][qq] = nrq; C[qq][rr] = nrq;
#pragma unroll
            for (int i = 0; i < 3; ++i) {
                const double vip = V[i][pp], viq = V[i][qq];
                V[i][pp] = c*vip - ss*viq;
                V[i][qq] = ss*vip + c*viq;
            }
        }
    }

    int idx = 0;
    if (C[1][1] < C[idx][idx]) idx = 1;
    if (C[2][2] < C[idx][idx]) idx = 2;
    double rx = V[0][idx], ry = V[1][idx], rz = V[2][idx];
    const double inv = 1.0 / sqrt(rx*rx + ry*ry + rz*rz);
    rx *= inv; ry *= inv; rz *= inv;

    const double nxd = (double)nrm[p*3+0];
    const double nyd = (double)nrm[p*3+1];
    const double nzd = (double)nrm[p*3+2];
    if (rx*nxd + ry*nyd + rz*nzd < 0.0) { rx = -rx; ry = -ry; rz = -rz; }
    const double rd = cx*rx + cy*ry + cz*rz;

    const float vldf = (float)valid;
    params[p*8+0] = nrm[p*3+0];
    params[p*8+1] = nrm[p*3+1];
    params[p*8+2] = nrm[p*3+2];
    params[p*8+3] = -dst[p];
    params[p*8+4] = vldf * (float)rx;
    params[p*8+5] = vldf * (float)ry;
    params[p*8+6] = vldf * (float)rz;
    params[p*8+7] = -(vldf * (float)rd);
}

// ---------------------------------------------------------------------------
// Stage 3: packed projection, 8 points per thread as 4 pairs (12 pk-inst per
// pair per plane; sign folded into the update fma via neg modifiers).
// ---------------------------------------------------------------------------
#define PPTH 8
#define PQ   (N_POINTS / PPTH)   // 500,000

__global__ __launch_bounds__(256)
void project_kernel(const float* __restrict__ pts,
                    const float* __restrict__ params,
                    float* __restrict__ out)
{
    const int tid = blockIdx.x * 256 + threadIdx.x;
    if (tid >= PQ) return;

    const v2f TH2N2 = { -(THRESH*THRESH), -(THRESH*THRESH) };
    const v2f NBIG2 = { -1e20f, -1e20f };

    v2f ox2[4], oy2[4], oz2[4], qx2[4], qy2[4], qz2[4];
#pragma unroll
    for (int k = 0; k < 4; ++k) {
        const long long i0 = (long long)tid + (long long)(2*k)   * PQ;
        const long long i1 = (long long)tid + (long long)(2*k+1) * PQ;
        ox2[k] = (v2f){ pts[i0*3+0], pts[i1*3+0] };
        oy2[k] = (v2f){ pts[i0*3+1], pts[i1*3+1] };
        oz2[k] = (v2f){ pts[i0*3+2], pts[i1*3+2] };
        qx2[k] = ox2[k]; qy2[k] = oy2[k]; qz2[k] = oz2[k];
    }

#pragma unroll 2
    for (int p = 0; p < N_PLANES; ++p) {
        const float nx  = params[p*8+0];
        const float ny  = params[p*8+1];
        const float nz  = params[p*8+2];
        const float md  = params[p*8+3];   // -d
        const float rvx = params[p*8+4];   // vld*rx
        const float rvy = params[p*8+5];
        const float rvz = params[p*8+6];
        const float mrd = params[p*8+7];   // -vld*rd
        const v2f nx2  = (v2f){nx,nx},   ny2  = (v2f){ny,ny},   nz2 = (v2f){nz,nz};
        const v2f md2  = (v2f){md,md},   mrd2 = (v2f){mrd,mrd};
        const v2f rvx2 = (v2f){rvx,rvx}, rvy2 = (v2f){rvy,rvy}, rvz2 = (v2f){rvz,rvz};

#pragma unroll
        for (int k = 0; k < 4; ++k) {
            const v2f t0  = pk_fma(ox2[k], nx2, pk_fma(oy2[k], ny2, pk_fma(oz2[k], nz2, md2)));
            const v2f d2  = pk_fma(t0, t0, TH2N2);
            const v2f fm2 = pk_mul_clamp(d2, NBIG2);
            const v2f tt  = pk_fma(qx2[k], rvx2, pk_fma(qy2[k], rvy2, pk_fma(qz2[k], rvz2, mrd2)));
            const v2f ft  = pk_mul(tt, fm2);                  // fm*t
            qx2[k] = pk_fma_n0(ft, rvx2, qx2[k]);             // q - ft*rv
            qy2[k] = pk_fma_n0(ft, rvy2, qy2[k]);
            qz2[k] = pk_fma_n0(ft, rvz2, qz2[k]);
        }
    }

#pragma unroll
    for (int k = 0; k < 4; ++k) {
        const long long i0 = (long long)tid + (long long)(2*k)   * PQ;
        const long long i1 = (long long)tid + (long long)(2*k+1) * PQ;
        out[i0*3+0] = qx2[k].x; out[i0*3+1] = qy2[k].x; out[i0*3+2] = qz2[k].x;
        out[i1*3+0] = qx2[k].y; out[i1*3+1] = qy2[k].y; out[i1*3+2] = qz2[k].y;
    }
}

// ---------------------------------------------------------------------------
extern "C" void kernel_launch(void* const* d_in, const int* in_sizes, int n_in,
                              void* d_out, int out_size, void* d_ws, size_t ws_size,
                              hipStream_t stream)
{
    const float* pts = (const float*)d_in[0];
    const float* nrm = (const float*)d_in[1];
    const float* dst = (const float*)d_in[2];
    float* out = (float*)d_out;

    float* partials = (float*)d_ws;                         // G1 x 640 f32 (5.24 MB)
    size_t poff = ((size_t)G1 * NVALS * sizeof(float) + 255) & ~(size_t)255;
    float* params = (float*)((char*)d_ws + poff);

    hipLaunchKernelGGL(reduce_kernel, dim3(G1), dim3(RTHR), 0, stream,
                       pts, nrm, dst, partials);
    hipLaunchKernelGGL(finalize_kernel, dim3(N_PLANES), dim3(256), 0, stream,
                       partials, G1, nrm, dst, params);
    hipLaunchKernelGGL(project_kernel, dim3((PQ + 255) / 256), dim3(256), 0, stream,
                       pts, params, out);
}

// Round 15
// 171.082 us; speedup vs baseline: 1.0615x; 1.0066x over previous
//
#include <hip/hip_runtime.h>
#include <math.h>

#define N_POINTS 4000000
#define N_PLANES 64
#define THRESH   0.02f
#define NVALS    (N_PLANES*10)              // 640
#define PPT      16                         // points per lane (8 packed pairs)
#define NPAIR    (PPT/2)
#define BLKPTS   (PPT*64)                   // 1024 points per item
#define G1       1024                       // reduce grid (single cohort @4 waves/SIMD)
#define ITEMS    4                          // items per block (uniform)
#define NPB      (G1*ITEMS)                 // 4096 items
#define NPAD     (NPB*BLKPTS - N_POINTS)    // 194,304 zero-padded points
#define FULL_PB  (N_POINTS/BLKPTS)          // 3906: items < this are fully valid
#define SEG_R    8                          // rotations per item (2 planes/lane)
#define RTHR     256                        // 4 waves per block

typedef float v2f __attribute__((ext_vector_type(2)));

// ---- packed fp32 primitives (VOP3P) ----
__device__ __forceinline__ v2f pk_fma(v2f a, v2f b, v2f c) {
    v2f d; asm("v_pk_fma_f32 %0, %1, %2, %3" : "=v"(d) : "v"(a), "v"(b), "v"(c)); return d;
}
__device__ __forceinline__ v2f pk_fma_n0(v2f a, v2f b, v2f c) {   // d = -a*b + c
    v2f d; asm("v_pk_fma_f32 %0, %1, %2, %3 neg_lo:[1,0,0] neg_hi:[1,0,0]"
               : "=v"(d) : "v"(a), "v"(b), "v"(c)); return d;
}
__device__ __forceinline__ v2f pk_mul(v2f a, v2f b) {
    v2f d; asm("v_pk_mul_f32 %0, %1, %2" : "=v"(d) : "v"(a), "v"(b)); return d;
}
__device__ __forceinline__ v2f pk_mul_clamp(v2f a, v2f b) {
    v2f d; asm("v_pk_mul_f32 %0, %1, %2 clamp" : "=v"(d) : "v"(a), "v"(b)); return d;
}
__device__ __forceinline__ void pk_adda(v2f& acc, v2f a) {
    asm("v_pk_add_f32 %0, %1, %0" : "+v"(acc) : "v"(a));
}
// splat variants: src0's LO (or HI) half feeds BOTH result halves (op_sel)
__device__ __forceinline__ v2f pk_fma_lo(v2f a, v2f b, v2f c) {  // {a.x*b.x+c.x, a.x*b.y+c.y}
    v2f d; asm("v_pk_fma_f32 %0, %1, %2, %3 op_sel:[0,0,0] op_sel_hi:[0,1,1]"
               : "=v"(d) : "v"(a), "v"(b), "v"(c)); return d;
}
__device__ __forceinline__ v2f pk_fma_hi(v2f a, v2f b, v2f c) {  // {a.y*b.x+c.x, a.y*b.y+c.y}
    v2f d; asm("v_pk_fma_f32 %0, %1, %2, %3 op_sel:[1,0,0] op_sel_hi:[1,1,1]"
               : "=v"(d) : "v"(a), "v"(b), "v"(c)); return d;
}
__device__ __forceinline__ void pk_fmaa_lo(v2f& acc, v2f a, v2f b) { // acc += a.x * b
    asm("v_pk_fma_f32 %0, %1, %2, %0 op_sel:[0,0,0] op_sel_hi:[0,1,1]"
        : "+v"(acc) : "v"(a), "v"(b));
}
__device__ __forceinline__ void pk_fmaa_hi(v2f& acc, v2f a, v2f b) { // acc += a.y * b
    asm("v_pk_fma_f32 %0, %1, %2, %0 op_sel:[1,0,0] op_sel_hi:[1,1,1]"
        : "+v"(acc) : "v"(a), "v"(b));
}
__device__ __forceinline__ v2f pk_mul_lo(v2f a, v2f b) {  // {a.x*b.x, a.x*b.y}
    v2f d; asm("v_pk_mul_f32 %0, %1, %2 op_sel:[0,0] op_sel_hi:[0,1]"
               : "=v"(d) : "v"(a), "v"(b)); return d;
}
__device__ __forceinline__ v2f pk_mul_hi(v2f a, v2f b) {  // {a.y*b.x, a.y*b.y}
    v2f d; asm("v_pk_mul_f32 %0, %1, %2 op_sel:[1,0] op_sel_hi:[1,1]"
               : "=v"(d) : "v"(a), "v"(b)); return d;
}
__device__ __forceinline__ float bperm(int addr, float v) {
    return __uint_as_float(__builtin_amdgcn_ds_bpermute(addr, __float_as_uint(v)));
}

// ---------------------------------------------------------------------------
// Stage 1: systolic reduction, TWO planes per lane (packed plane dimension).
// Lane l holds 16 points (8 packed pairs) + planes {qA, qA+32} as packed
// params {nA,nB} and 10 packed accumulators {accA, accB}. Each point is
// consumed via op_sel splat against both planes at once: 18 pk per point
// (9 per point-plane, unchanged), but NO per-rotation VALU fold and only
// 8 rotation boundaries per item (each rotation = 20 tot-bperms; params
// prefetched from nrm/dst on the VMEM pipe). Coverage: wave w, item k covers
// plane-offsets 8k+[8w,8w+8) and +32 -> all 64 exactly once per point.
// Zero-pads contribute only to cnt iff fmaf(d,d,-TH^2)<0; finalize subtracts.
// ---------------------------------------------------------------------------
__global__ __launch_bounds__(RTHR, 4)
void reduce_kernel(const float* __restrict__ pts,
                   const float* __restrict__ nrm,
                   const float* __restrict__ dst,
                   float* __restrict__ partials)
{
    const int lane = threadIdx.x & 63;
    const int wid  = threadIdx.x >> 6;

    __shared__ float part[RTHR/64][NVALS];

    const int rotaddr = ((lane + 1) & 63) << 2;   // pull from lane+1

    const v2f TH2N2 = { -(THRESH*THRESH), -(THRESH*THRESH) };
    const v2f NBIG2 = { -1e20f, -1e20f };

    // resident planes: qA = (lane + 8*wid), qB = qA+32; packed params {A,B}
    int qA = (lane + SEG_R * wid) & 63;
    v2f nxpk, nypk, nzpk, ndpk;
    {
        const int qB = (qA + 32) & 63;
        nxpk = (v2f){ nrm[qA*3+0], nrm[qB*3+0] };
        nypk = (v2f){ nrm[qA*3+1], nrm[qB*3+1] };
        nzpk = (v2f){ nrm[qA*3+2], nrm[qB*3+2] };
        ndpk = (v2f){ -dst[qA],    -dst[qB]    };
    }

    v2f T0={0,0},T1={0,0},T2={0,0},T3={0,0},T4={0,0};
    v2f T5={0,0},T6={0,0},T7={0,0},T8={0,0},T9={0,0};

    v2f PX2[NPAIR], PY2[NPAIR], PZ2[NPAIR];

    for (int it = 0; it < ITEMS; ++it) {
        const int pb = blockIdx.x * ITEMS + it;
        const float* P0 = pts + ((size_t)pb * BLKPTS + lane) * 3;

        if (pb < FULL_PB) {                       // fully valid (fast path)
#pragma unroll
            for (int v = 0; v < NPAIR; ++v) {
                PX2[v] = (v2f){ P0[(2*v)*192+0], P0[(2*v+1)*192+0] };
                PY2[v] = (v2f){ P0[(2*v)*192+1], P0[(2*v+1)*192+1] };
                PZ2[v] = (v2f){ P0[(2*v)*192+2], P0[(2*v+1)*192+2] };
            }
        } else if (pb == FULL_PB) {               // first 256 points valid: v<2
#pragma unroll
            for (int v = 0; v < NPAIR; ++v) {
                if (v < 2) {
                    PX2[v] = (v2f){ P0[(2*v)*192+0], P0[(2*v+1)*192+0] };
                    PY2[v] = (v2f){ P0[(2*v)*192+1], P0[(2*v+1)*192+1] };
                    PZ2[v] = (v2f){ P0[(2*v)*192+2], P0[(2*v+1)*192+2] };
                } else {
                    PX2[v] = (v2f){0.f,0.f}; PY2[v] = (v2f){0.f,0.f}; PZ2[v] = (v2f){0.f,0.f};
                }
            }
        } else {                                  // pure pad item
#pragma unroll
            for (int v = 0; v < NPAIR; ++v) {
                PX2[v] = (v2f){0.f,0.f}; PY2[v] = (v2f){0.f,0.f}; PZ2[v] = (v2f){0.f,0.f};
            }
        }

#pragma unroll 1
        for (int r = 0; r < SEG_R; ++r) {
            // prefetch next rotation's params (VMEM, hidden under point loop)
            const int qn = (qA + 1) & 63;
            const int qm = (qn + 32) & 63;
            const float fnxA = nrm[qn*3+0], fnxB = nrm[qm*3+0];
            const float fnyA = nrm[qn*3+1], fnyB = nrm[qm*3+1];
            const float fnzA = nrm[qn*3+2], fnzB = nrm[qm*3+2];
            const float fndA = -dst[qn],    fndB = -dst[qm];

#pragma unroll
            for (int v = 0; v < NPAIR; ++v) {
                {   // even point (lo half), both planes at once
                    const v2f t2  = pk_fma_lo(PX2[v], nxpk,
                                    pk_fma_lo(PY2[v], nypk,
                                    pk_fma_lo(PZ2[v], nzpk, ndpk)));
                    const v2f d2  = pk_fma(t2, t2, TH2N2);
                    const v2f fm2 = pk_mul_clamp(d2, NBIG2);   // {mA, mB}
                    const v2f tx2 = pk_mul_lo(PX2[v], fm2);
                    const v2f ty2 = pk_mul_lo(PY2[v], fm2);
                    const v2f tz2 = pk_mul_lo(PZ2[v], fm2);
                    pk_adda(T0, fm2);
                    pk_adda(T1, tx2); pk_adda(T2, ty2); pk_adda(T3, tz2);
                    pk_fmaa_lo(T4, PX2[v], tx2); pk_fmaa_lo(T5, PY2[v], tx2);
                    pk_fmaa_lo(T6, PZ2[v], tx2); pk_fmaa_lo(T7, PY2[v], ty2);
                    pk_fmaa_lo(T8, PZ2[v], ty2); pk_fmaa_lo(T9, PZ2[v], tz2);
                }
                {   // odd point (hi half)
                    const v2f t2  = pk_fma_hi(PX2[v], nxpk,
                                    pk_fma_hi(PY2[v], nypk,
                                    pk_fma_hi(PZ2[v], nzpk, ndpk)));
                    const v2f d2  = pk_fma(t2, t2, TH2N2);
                    const v2f fm2 = pk_mul_clamp(d2, NBIG2);
                    const v2f tx2 = pk_mul_hi(PX2[v], fm2);
                    const v2f ty2 = pk_mul_hi(PY2[v], fm2);
                    const v2f tz2 = pk_mul_hi(PZ2[v], fm2);
                    pk_adda(T0, fm2);
                    pk_adda(T1, tx2); pk_adda(T2, ty2); pk_adda(T3, tz2);
                    pk_fmaa_hi(T4, PX2[v], tx2); pk_fmaa_hi(T5, PY2[v], tx2);
                    pk_fmaa_hi(T6, PZ2[v], tx2); pk_fmaa_hi(T7, PY2[v], ty2);
                    pk_fmaa_hi(T8, PZ2[v], ty2); pk_fmaa_hi(T9, PZ2[v], tz2);
                }
            }

            // rotate packed tots one lane over (both halves; no VALU fold)
            T0.x = bperm(rotaddr, T0.x); T0.y = bperm(rotaddr, T0.y);
            T1.x = bperm(rotaddr, T1.x); T1.y = bperm(rotaddr, T1.y);
            T2.x = bperm(rotaddr, T2.x); T2.y = bperm(rotaddr, T2.y);
            T3.x = bperm(rotaddr, T3.x); T3.y = bperm(rotaddr, T3.y);
            T4.x = bperm(rotaddr, T4.x); T4.y = bperm(rotaddr, T4.y);
            T5.x = bperm(rotaddr, T5.x); T5.y = bperm(rotaddr, T5.y);
            T6.x = bperm(rotaddr, T6.x); T6.y = bperm(rotaddr, T6.y);
            T7.x = bperm(rotaddr, T7.x); T7.y = bperm(rotaddr, T7.y);
            T8.x = bperm(rotaddr, T8.x); T8.y = bperm(rotaddr, T8.y);
            T9.x = bperm(rotaddr, T9.x); T9.y = bperm(rotaddr, T9.y);

            // install prefetched params
            nxpk = (v2f){fnxA, fnxB}; nypk = (v2f){fnyA, fnyB};
            nzpk = (v2f){fnzA, fnzB}; ndpk = (v2f){fndA, fndB};
            qA = qn;
        }
    }

    // after SEG_R*ITEMS = 32 rotations, lane l holds planes
    // wpA = (l + 8*wid + 32) & 63 (half A) and wpB = wpA+32 (half B).
    {
        const int wpA = (lane + SEG_R * wid + SEG_R * ITEMS) & 63;
        const int wpB = (wpA + 32) & 63;
        float* rA = &part[wid][wpA * 10];
        rA[0]=T0.x; rA[1]=T1.x; rA[2]=T2.x; rA[3]=T3.x; rA[4]=T4.x;
        rA[5]=T5.x; rA[6]=T6.x; rA[7]=T7.x; rA[8]=T8.x; rA[9]=T9.x;
        // B-half accumulates into rows written by the A-half of lane+32
        float* rB = &part[wid][wpB * 10];
        rB[0]+=T0.y; rB[1]+=T1.y; rB[2]+=T2.y; rB[3]+=T3.y; rB[4]+=T4.y;
        rB[5]+=T5.y; rB[6]+=T6.y; rB[7]+=T7.y; rB[8]+=T8.y; rB[9]+=T9.y;
    }
    __syncthreads();
    for (int v = threadIdx.x; v < NVALS; v += RTHR) {
        float sum = 0.f;
#pragma unroll
        for (int ww = 0; ww < RTHR/64; ++ww) sum += part[ww][v];
        partials[(long long)blockIdx.x * NVALS + v] = sum;
    }
}

// ---------------------------------------------------------------------------
// Stage 2 (fused fit): one block per plane. Stream partials, f64-accumulate,
// subtract the zero-pad cnt contamination (bit-identical predicate to the
// kernel's packed mask), then thread 0 runs the 3x3 Jacobi eigensolve and
// writes the merged param row {nx,ny,nz,-d, vld*rx,vld*ry,vld*rz, -vld*rd}.
// ---------------------------------------------------------------------------
__global__ __launch_bounds__(256)
void finalize_kernel(const float* __restrict__ partials, int nb,
                     const float* __restrict__ nrm,
                     const float* __restrict__ dst,
                     float* __restrict__ params)
{
    const int p    = blockIdx.x;
    const int lane = threadIdx.x & 63;
    const int wid  = threadIdx.x >> 6;

    double s[10];
#pragma unroll
    for (int q = 0; q < 10; ++q) s[q] = 0.0;

    for (int b = threadIdx.x; b < nb; b += 256) {
        const float* row = partials + (long long)b * NVALS + p * 10;
#pragma unroll
        for (int q = 0; q < 10; ++q) s[q] += (double)row[q];
    }

#pragma unroll
    for (int off = 32; off; off >>= 1)
#pragma unroll
        for (int q = 0; q < 10; ++q) s[q] += __shfl_xor(s[q], off);

    __shared__ double wsum[4][10];
    if (lane == 0) {
#pragma unroll
        for (int q = 0; q < 10; ++q) wsum[wid][q] = s[q];
    }
    __syncthreads();
    if (threadIdx.x != 0) return;

    double acc[10];
#pragma unroll
    for (int q = 0; q < 10; ++q)
        acc[q] = wsum[0][q] + wsum[1][q] + wsum[2][q] + wsum[3][q];

    double cnt = acc[0];
    // pad points (0,0,0): t = -d; mask = clamp((t^2 - TH^2) * -1e20) = 1
    if (fmaf(dst[p], dst[p], -(THRESH*THRESH)) < 0.0f) cnt -= (double)NPAD;

    const double sx = acc[1], sy = acc[2], sz = acc[3];
    const double den = fmax(cnt, 1.0);
    const double cx = sx / den, cy = sy / den, cz = sz / den;

    double C[3][3];
    C[0][0] = acc[4] - 2.0*cx*sx + cnt*cx*cx;
    C[0][1] = acc[5] - cx*sy - cy*sx + cnt*cx*cy;
    C[0][2] = acc[6] - cx*sz - cz*sx + cnt*cx*cz;
    C[1][1] = acc[7] - 2.0*cy*sy + cnt*cy*cy;
    C[1][2] = acc[8] - cy*sz - cz*sy + cnt*cy*cz;
    C[2][2] = acc[9] - 2.0*cz*sz + cnt*cz*cz;
    C[1][0] = C[0][1]; C[2][0] = C[0][2]; C[2][1] = C[1][2];

    const double valid = (cnt >= 3.0) ? 1.0 : 0.0;
    C[0][0] += (1.0 - valid) * 1.0;
    C[1][1] += (1.0 - valid) * 2.0;
    C[2][2] += (1.0 - valid) * 3.0;

    double V[3][3] = {{1,0,0},{0,1,0},{0,0,1}};
    for (int sweep = 0; sweep < 15; ++sweep) {
#pragma unroll
        for (int k = 0; k < 3; ++k) {
            const int pp = (k == 2) ? 1 : 0;
            const int qq = (k == 0) ? 1 : 2;
            const int rr = 3 - pp - qq;
            const double apq = C[pp][qq];
            if (fabs(apq) < 1e-300) continue;
            const double theta = (C[qq][qq] - C[pp][pp]) / (2.0 * apq);
            const double t = copysign(1.0, theta) / (fabs(theta) + sqrt(theta*theta + 1.0));
            const double c = 1.0 / sqrt(t*t + 1.0);
            const double ss = t * c;
            const double app = C[pp][pp], aqq = C[qq][qq];
            const double arp = C[rr][pp], arq = C[rr][qq];
            C[pp][pp] = app - t * apq;
            C[qq][qq] = aqq + t * apq;
            C[pp][qq] = 0.0; C[qq][pp] = 0.0;
            const double nrp = c*arp - ss*arq;
            const double nrq = ss*arp + c*arq;
            C[rr][pp] = nrp; C[pp][rr] = nrp;
            C[rr][qq] = nrq; C[qq][rr] = nrq;
#pragma unroll
            for (int i = 0; i < 3; ++i) {
                const double vip = V[i][pp], viq = V[i][qq];
                V[i][pp] = c*vip - ss*viq;
                V[i][qq] = ss*vip + c*viq;
            }
        }
    }

    int idx = 0;
    if (C[1][1] < C[idx][idx]) idx = 1;
    if (C[2][2] < C[idx][idx]) idx = 2;
    double rx = V[0][idx], ry = V[1][idx], rz = V[2][idx];
    const double inv = 1.0 / sqrt(rx*rx + ry*ry + rz*rz);
    rx *= inv; ry *= inv; rz *= inv;

    const double nxd = (double)nrm[p*3+0];
    const double nyd = (double)nrm[p*3+1];
    const double nzd = (double)nrm[p*3+2];
    if (rx*nxd + ry*nyd + rz*nzd < 0.0) { rx = -rx; ry = -ry; rz = -rz; }
    const double rd = cx*rx + cy*ry + cz*rz;

    const float vldf = (float)valid;
    params[p*8+0] = nrm[p*3+0];
    params[p*8+1] = nrm[p*3+1];
    params[p*8+2] = nrm[p*3+2];
    params[p*8+3] = -dst[p];
    params[p*8+4] = vldf * (float)rx;
    params[p*8+5] = vldf * (float)ry;
    params[p*8+6] = vldf * (float)rz;
    params[p*8+7] = -(vldf * (float)rd);
}

// ---------------------------------------------------------------------------
// Stage 3: packed projection, 8 points per thread as 4 pairs (12 pk-inst per
// pair per plane; sign folded into the update fma via neg modifiers).
// ---------------------------------------------------------------------------
#define PPTH 8
#define PQ   (N_POINTS / PPTH)   // 500,000

__global__ __launch_bounds__(256)
void project_kernel(const float* __restrict__ pts,
                    const float* __restrict__ params,
                    float* __restrict__ out)
{
    const int tid = blockIdx.x * 256 + threadIdx.x;
    if (tid >= PQ) return;

    const v2f TH2N2 = { -(THRESH*THRESH), -(THRESH*THRESH) };
    const v2f NBIG2 = { -1e20f, -1e20f };

    v2f ox2[4], oy2[4], oz2[4], qx2[4], qy2[4], qz2[4];
#pragma unroll
    for (int k = 0; k < 4; ++k) {
        const long long i0 = (long long)tid + (long long)(2*k)   * PQ;
        const long long i1 = (long long)tid + (long long)(2*k+1) * PQ;
        ox2[k] = (v2f){ pts[i0*3+0], pts[i1*3+0] };
        oy2[k] = (v2f){ pts[i0*3+1], pts[i1*3+1] };
        oz2[k] = (v2f){ pts[i0*3+2], pts[i1*3+2] };
        qx2[k] = ox2[k]; qy2[k] = oy2[k]; qz2[k] = oz2[k];
    }

#pragma unroll 2
    for (int p = 0; p < N_PLANES; ++p) {
        const float nx  = params[p*8+0];
        const float ny  = params[p*8+1];
        const float nz  = params[p*8+2];
        const float md  = params[p*8+3];   // -d
        const float rvx = params[p*8+4];   // vld*rx
        const float rvy = params[p*8+5];
        const float rvz = params[p*8+6];
        const float mrd = params[p*8+7];   // -vld*rd
        const v2f nx2  = (v2f){nx,nx},   ny2  = (v2f){ny,ny},   nz2 = (v2f){nz,nz};
        const v2f md2  = (v2f){md,md},   mrd2 = (v2f){mrd,mrd};
        const v2f rvx2 = (v2f){rvx,rvx}, rvy2 = (v2f){rvy,rvy}, rvz2 = (v2f){rvz,rvz};

#pragma unroll
        for (int k = 0; k < 4; ++k) {
            const v2f t0  = pk_fma(ox2[k], nx2, pk_fma(oy2[k], ny2, pk_fma(oz2[k], nz2, md2)));
            const v2f d2  = pk_fma(t0, t0, TH2N2);
            const v2f fm2 = pk_mul_clamp(d2, NBIG2);
            const v2f tt  = pk_fma(qx2[k], rvx2, pk_fma(qy2[k], rvy2, pk_fma(qz2[k], rvz2, mrd2)));
            const v2f ft  = pk_mul(tt, fm2);                  // fm*t
            qx2[k] = pk_fma_n0(ft, rvx2, qx2[k]);             // q - ft*rv
            qy2[k] = pk_fma_n0(ft, rvy2, qy2[k]);
            qz2[k] = pk_fma_n0(ft, rvz2, qz2[k]);
        }
    }

#pragma unroll
    for (int k = 0; k < 4; ++k) {
        const long long i0 = (long long)tid + (long long)(2*k)   * PQ;
        const long long i1 = (long long)tid + (long long)(2*k+1) * PQ;
        out[i0*3+0] = qx2[k].x; out[i0*3+1] = qy2[k].x; out[i0*3+2] = qz2[k].x;
        out[i1*3+0] = qx2[k].y; out[i1*3+1] = qy2[k].y; out[i1*3+2] = qz2[k].y;
    }
}

// ---------------------------------------------------------------------------
extern "C" void kernel_launch(void* const* d_in, const int* in_sizes, int n_in,
                              void* d_out, int out_size, void* d_ws, size_t ws_size,
                              hipStream_t stream)
{
    const float* pts = (const float*)d_in[0];
    const float* nrm = (const float*)d_in[1];
    const float* dst = (const float*)d_in[2];
    float* out = (float*)d_out;

    float* partials = (float*)d_ws;                         // G1 x 640 f32 (2.62 MB)
    size_t poff = ((size_t)G1 * NVALS * sizeof(float) + 255) & ~(size_t)255;
    float* params = (float*)((char*)d_ws + poff);

    hipLaunchKernelGGL(reduce_kernel, dim3(G1), dim3(RTHR), 0, stream,
                       pts, nrm, dst, partials);
    hipLaunchKernelGGL(finalize_kernel, dim3(N_PLANES), dim3(256), 0, stream,
                       partials, G1, nrm, dst, params);
    hipLaunchKernelGGL(project_kernel, dim3((PQ + 255) / 256), dim3(256), 0, stream,
                       pts, params, out);
}